// Round 2
// baseline (463.776 us; speedup 1.0000x reference)
//
#include <hip/hip_runtime.h>
#include <stdint.h>

typedef __attribute__((ext_vector_type(8))) __bf16 bf16x8;
typedef __attribute__((ext_vector_type(4))) float f32x4;
typedef __attribute__((ext_vector_type(4))) unsigned short us4;

__device__ __forceinline__ unsigned short f2b(float f){
  unsigned int u = __builtin_bit_cast(unsigned int, f);
  unsigned int r = (u + 0x7fffu + ((u >> 16) & 1u)) >> 16;
  return (unsigned short)r;
}
__device__ __forceinline__ float b2f(unsigned short h){
  unsigned int u = ((unsigned int)h) << 16;
  return __builtin_bit_cast(float, u);
}

#define KDIM 1024
#define NDIM 1024

// ---------------- prep kernels ----------------

__global__ void k_cast_bf16(const float* __restrict__ in, unsigned short* __restrict__ out, int n4){
  int i = blockIdx.x * 256 + threadIdx.x;
  if (i < n4){
    float4 v = ((const float4*)in)[i];
    us4 o; o.x = f2b(v.x); o.y = f2b(v.y); o.z = f2b(v.z); o.w = f2b(v.w);
    ((us4*)out)[i] = o;
  }
}

// out[b][c][r] = in[b][r][c], cast to bf16
__global__ void k_transpose_cast(const float* __restrict__ in, unsigned short* __restrict__ out,
                                 int rows, int cols, int total){
  int idx = blockIdx.x * 256 + threadIdx.x;
  if (idx >= total) return;
  int rc = rows * cols;
  int b = idx / rc, rem = idx - b * rc;
  int c = rem / rows, r = rem - c * rows;
  out[idx] = f2b(in[(size_t)b * rc + (size_t)r * cols + c]);
}

// h_q[r] = sum_n allh[n*128+r]*fwq[n];  g_q[n*128+r] = rwq[n]*h_q[r]   (same for k)
__global__ __launch_bounds__(128) void k_mix_qk(const unsigned short* __restrict__ allh,
    const float* __restrict__ fwq, const float* __restrict__ fwk,
    const float* __restrict__ rwq, const float* __restrict__ rwk,
    unsigned short* __restrict__ gq, unsigned short* __restrict__ gk){
  int bs = blockIdx.x; int r = threadIdx.x;
  const unsigned short* ah = allh + (size_t)bs * 1024;
  float hq = 0.f, hk = 0.f;
  float fq[8], fk[8], rq[8], rk[8];
  #pragma unroll
  for (int n = 0; n < 8; n++){ fq[n] = fwq[bs*8+n]; fk[n] = fwk[bs*8+n]; rq[n] = rwq[bs*8+n]; rk[n] = rwk[bs*8+n]; }
  #pragma unroll
  for (int n = 0; n < 8; n++){ float a = b2f(ah[n*128 + r]); hq += a * fq[n]; hk += a * fk[n]; }
  #pragma unroll
  for (int n = 0; n < 8; n++){
    gq[(size_t)bs*1024 + n*128 + r] = f2b(rq[n] * hq);
    gk[(size_t)bs*1024 + n*128 + r] = f2b(rk[n] * hk);
  }
}

__global__ __launch_bounds__(128) void k_mix_v(const unsigned short* __restrict__ allh,
    const float* __restrict__ fwv, const float* __restrict__ rwv,
    unsigned short* __restrict__ gv){
  int bs = blockIdx.x; int r = threadIdx.x;
  const unsigned short* ah = allh + (size_t)bs * 1024;
  float hv = 0.f;
  float fv[8], rv[8];
  #pragma unroll
  for (int n = 0; n < 8; n++){ fv[n] = fwv[bs*8+n]; rv[n] = rwv[bs*8+n]; }
  #pragma unroll
  for (int n = 0; n < 8; n++){ hv += b2f(ah[n*128 + r]) * fv[n]; }
  #pragma unroll
  for (int n = 0; n < 8; n++){ gv[(size_t)bs*1024 + n*128 + r] = f2b(rv[n] * hv); }
}

// Vt[(bh*64+dh)][s] = Vb[(b*2048+s)][h*64+dh]
__global__ void k_transpose_v(const unsigned short* __restrict__ Vb, unsigned short* __restrict__ Vt){
  int idx = blockIdx.x * 256 + threadIdx.x;
  int s = idx & 2047, row = idx >> 11;
  int bh = row >> 6, dh = row & 63, b = bh >> 4, h = bh & 15;
  Vt[idx] = Vb[((size_t)(b*2048 + s)) * 1024 + h*64 + dh];
}

// ---------------- GEMM: C[M,N] = A[M,K] @ Bt[N,K]^T, bf16 in, f32 acc ----------------

__device__ __forceinline__ void load_lds16(const void* g, void* l){
  __builtin_amdgcn_global_load_lds((const __attribute__((address_space(1))) unsigned int*)g,
                                   (__attribute__((address_space(3))) unsigned int*)l, 16, 0, 0);
}

template<int OUT_BF16>
__global__ __launch_bounds__(256) void k_gemm_bt3(
    const unsigned short* __restrict__ A0, const unsigned short* __restrict__ B0, void* __restrict__ C0,
    const unsigned short* __restrict__ A1, const unsigned short* __restrict__ B1, void* __restrict__ C1,
    const unsigned short* __restrict__ A2, const unsigned short* __restrict__ B2, void* __restrict__ C2)
{
  __shared__ unsigned short Al[2][128*32];
  __shared__ unsigned short Bl[2][128*32];
  int job = blockIdx.x >> 8;
  int bid = blockIdx.x & 255;
  const unsigned short* A  = job == 0 ? A0 : (job == 1 ? A1 : A2);
  const unsigned short* Bt = job == 0 ? B0 : (job == 1 ? B1 : B2);
  void* C = job == 0 ? C0 : (job == 1 ? C1 : C2);
  int bx = bid & 7, by = bid >> 3;
  int m0 = by * 128, n0 = bx * 128;
  int tid = threadIdx.x, wid = tid >> 6, lane = tid & 63, l15 = lane & 15, g = lane >> 4;
  int wr = wid >> 1, wc = wid & 1;

  auto stage = [&](int buf, int kt){
    #pragma unroll
    for (int i = 0; i < 2; i++){
      int c = i * 256 + tid;
      load_lds16(A + (size_t)(m0 + (c >> 2)) * KDIM + kt * 32 + (c & 3) * 8,
                 &Al[buf][(i * 256 + wid * 64) * 8]);
    }
    #pragma unroll
    for (int i = 0; i < 2; i++){
      int c = i * 256 + tid;
      load_lds16(Bt + (size_t)(n0 + (c >> 2)) * KDIM + kt * 32 + (c & 3) * 8,
                 &Bl[buf][(i * 256 + wid * 64) * 8]);
    }
  };

  f32x4 acc[4][4] = {};

  stage(0, 0);
  __syncthreads();
  int cur = 0;
  const int nk = KDIM / 32;
  for (int kt = 0; kt < nk; ++kt){
    if (kt + 1 < nk) stage(cur ^ 1, kt + 1);
    bf16x8 af[4], bfv[4];
    #pragma unroll
    for (int mi = 0; mi < 4; mi++)
      af[mi] = *(const bf16x8*)&Al[cur][(wr*64 + mi*16 + l15) * 32 + g * 8];
    #pragma unroll
    for (int ni = 0; ni < 4; ni++)
      bfv[ni] = *(const bf16x8*)&Bl[cur][(wc*64 + ni*16 + l15) * 32 + g * 8];
    #pragma unroll
    for (int mi = 0; mi < 4; mi++)
      #pragma unroll
      for (int ni = 0; ni < 4; ni++)
        acc[mi][ni] = __builtin_amdgcn_mfma_f32_16x16x32_bf16(af[mi], bfv[ni], acc[mi][ni], 0, 0, 0);
    __syncthreads();
    cur ^= 1;
  }

  #pragma unroll
  for (int mi = 0; mi < 4; mi++){
    #pragma unroll
    for (int reg = 0; reg < 4; reg++){
      int row = m0 + wr*64 + mi*16 + g*4 + reg;
      #pragma unroll
      for (int ni = 0; ni < 4; ni++){
        int col = n0 + wc*64 + ni*16 + l15;
        float v = acc[mi][ni][reg];
        if (OUT_BF16) ((unsigned short*)C)[(size_t)row * NDIM + col] = f2b(v);
        else          ((float*)C)[(size_t)row * NDIM + col] = v;
      }
    }
  }
}

// ---------------- causal flash attention ----------------
// Q,K: [4096][1024] bf16 (token-major, head h at cols h*64..h*64+63)
// Vt:  [2048][2048] bf16, row = bh*64+dh, col = s
// AO:  [4096][1024] bf16
// Block: 4 waves x 16 q-rows = 64 q-rows; KV tile = 128.
#define PSTR 136  // padded LDS row stride (bf16 elems), 16B aligned
__global__ __launch_bounds__(256) void k_attn(
    const unsigned short* __restrict__ Qb, const unsigned short* __restrict__ Kb,
    const unsigned short* __restrict__ Vt, unsigned short* __restrict__ AO)
{
  __shared__ unsigned short Plds[4][16*PSTR];
  int qt = blockIdx.x & 31, bh = blockIdx.x >> 5, b = bh >> 4, h = bh & 15;
  int tid = threadIdx.x, w = tid >> 6, lane = tid & 63, l15 = lane & 15, g = lane >> 4;
  int q0 = qt * 64;
  const unsigned short* Qp = Qb + ((size_t)(b*2048 + q0 + w*16)) * 1024 + h*64;
  const unsigned short* Kp = Kb + (size_t)b * 2048 * 1024 + h*64;
  const unsigned short* Vp = Vt + (size_t)bh * 64 * 2048;
  unsigned short* Pw = &Plds[w][0];

  bf16x8 aq[2];
  #pragma unroll
  for (int kk = 0; kk < 2; kk++)
    aq[kk] = *(const bf16x8*)(Qp + (size_t)l15 * 1024 + kk*32 + g*8);

  const float cs = 0.125f * 1.44269504f;  // 1/sqrt(64) folded into log2 domain
  float m2[4], l_run[4];
  f32x4 acc_o[4] = {};
  #pragma unroll
  for (int r = 0; r < 4; r++){ m2[r] = -1e30f; l_run[r] = 0.f; }

  auto iter = [&](int t, bool partial){
    int kv0 = t * 128;
    f32x4 s[8];
    #pragma unroll
    for (int ti = 0; ti < 8; ti++) s[ti] = (f32x4){0.f,0.f,0.f,0.f};
    #pragma unroll
    for (int ti = 0; ti < 8; ti++){
      #pragma unroll
      for (int kk = 0; kk < 2; kk++){
        bf16x8 bk = *(const bf16x8*)(Kp + (size_t)(kv0 + ti*16 + l15) * 1024 + kk*32 + g*8);
        s[ti] = __builtin_amdgcn_mfma_f32_16x16x32_bf16(aq[kk], bk, s[ti], 0, 0, 0);
      }
    }
    #pragma unroll
    for (int reg = 0; reg < 4; reg++){
      int row = q0 + w*16 + g*4 + reg;
      float vv[8];
      #pragma unroll
      for (int ti = 0; ti < 8; ti++){
        float x = s[ti][reg] * cs;
        if (partial){
          int col = kv0 + ti*16 + l15;
          if (col > row) x = -1e30f;
        }
        vv[ti] = x;
      }
      float m01 = fmaxf(vv[0], vv[1]), m23 = fmaxf(vv[2], vv[3]);
      float m45 = fmaxf(vv[4], vv[5]), m67 = fmaxf(vv[6], vv[7]);
      float mt = fmaxf(fmaxf(m01, m23), fmaxf(m45, m67));
      #pragma unroll
      for (int off = 1; off < 16; off <<= 1) mt = fmaxf(mt, __shfl_xor(mt, off));
      float mn = fmaxf(m2[reg], mt);
      float corr = exp2f(m2[reg] - mn);
      m2[reg] = mn;
      float ps = 0.f;
      #pragma unroll
      for (int ti = 0; ti < 8; ti++){
        float p = exp2f(vv[ti] - mn);
        ps += p;
        Pw[(g*4 + reg)*PSTR + ti*16 + l15] = f2b(p);
      }
      #pragma unroll
      for (int off = 1; off < 16; off <<= 1) ps += __shfl_xor(ps, off);
      l_run[reg] = l_run[reg] * corr + ps;
      #pragma unroll
      for (int ni = 0; ni < 4; ni++) acc_o[ni][reg] *= corr;
    }
    bf16x8 pa[4];
    #pragma unroll
    for (int c = 0; c < 4; c++)
      pa[c] = *(const bf16x8*)&Pw[l15*PSTR + c*32 + g*8];
    #pragma unroll
    for (int ni = 0; ni < 4; ni++){
      #pragma unroll
      for (int c = 0; c < 4; c++){
        bf16x8 bv = *(const bf16x8*)(Vp + (size_t)(ni*16 + l15) * 2048 + kv0 + c*32 + g*8);
        acc_o[ni] = __builtin_amdgcn_mfma_f32_16x16x32_bf16(pa[c], bv, acc_o[ni], 0, 0, 0);
      }
    }
  };

  int ntot = (q0 + 63) / 128 + 1;
  for (int t = 0; t < ntot - 1; ++t) iter(t, false);
  iter(ntot - 1, true);

  #pragma unroll
  for (int ni = 0; ni < 4; ni++){
    #pragma unroll
    for (int reg = 0; reg < 4; reg++){
      int row = q0 + w*16 + g*4 + reg;
      int dh = ni*16 + l15;
      AO[((size_t)(b*2048 + row)) * 1024 + h*64 + dh] = f2b(acc_o[ni][reg] / l_run[reg]);
    }
  }
}

// ---------------- launch ----------------

extern "C" void kernel_launch(void* const* d_in, const int* in_sizes, int n_in,
                              void* d_out, int out_size, void* d_ws, size_t ws_size,
                              hipStream_t stream){
  const float* x    = (const float*)d_in[0];
  const float* fqk  = (const float*)d_in[1];
  const float* fv   = (const float*)d_in[2];
  const float* rqk  = (const float*)d_in[3];
  const float* rv   = (const float*)d_in[4];
  const float* fwQ  = (const float*)d_in[5];
  const float* fwK  = (const float*)d_in[6];
  const float* fwV  = (const float*)d_in[7];
  const float* rwQ  = (const float*)d_in[8];
  const float* rwK  = (const float*)d_in[9];
  const float* rwV  = (const float*)d_in[10];
  const float* wo   = (const float*)d_in[11];
  float* out = (float*)d_out;

  char* ws = (char*)d_ws;
  size_t off = 0;
  auto alloc = [&](size_t bytes)->void*{
    void* p = ws + off; off += (bytes + 255) & ~(size_t)255; return p;
  };
  unsigned short* Xbf  = (unsigned short*)alloc(4096ull*1024*2);
  unsigned short* FqkT = (unsigned short*)alloc(1024ull*1024*2);
  unsigned short* FvT  = (unsigned short*)alloc(1024ull*1024*2);
  unsigned short* RqkT = (unsigned short*)alloc(1024ull*1024*2);
  unsigned short* RvT  = (unsigned short*)alloc(1024ull*1024*2);
  unsigned short* WOT  = (unsigned short*)alloc(1024ull*1024*2);
  unsigned short* AHqk = (unsigned short*)alloc(4096ull*1024*2);
  unsigned short* AHv  = (unsigned short*)alloc(4096ull*1024*2);
  unsigned short* Gq   = (unsigned short*)alloc(4096ull*1024*2);
  unsigned short* Gk   = (unsigned short*)alloc(4096ull*1024*2);
  unsigned short* Gv   = (unsigned short*)alloc(4096ull*1024*2);
  unsigned short* Qm   = (unsigned short*)alloc(4096ull*1024*2);
  unsigned short* Km   = (unsigned short*)alloc(4096ull*1024*2);
  unsigned short* Vm   = (unsigned short*)alloc(4096ull*1024*2);
  unsigned short* Vtr  = (unsigned short*)alloc(2048ull*2048*2);
  unsigned short* AOm  = (unsigned short*)alloc(4096ull*1024*2);

  // pack/cast
  k_cast_bf16<<<4096, 256, 0, stream>>>(x, Xbf, 4096*1024/4);
  k_transpose_cast<<<4096, 256, 0, stream>>>(fqk, FqkT, 1024, 128, 8*1024*128);
  k_transpose_cast<<<4096, 256, 0, stream>>>(fv,  FvT,  1024, 128, 8*1024*128);
  k_transpose_cast<<<4096, 256, 0, stream>>>(rqk, RqkT, 1024, 1024, 1024*1024);
  k_transpose_cast<<<4096, 256, 0, stream>>>(rv,  RvT,  1024, 1024, 1024*1024);
  k_transpose_cast<<<4096, 256, 0, stream>>>(wo,  WOT,  1024, 1024, 1024*1024);

  // feature GEMMs: all_h = X @ F^T  (2 jobs)
  k_gemm_bt3<1><<<512, 256, 0, stream>>>(Xbf, FqkT, AHqk, Xbf, FvT, AHv,
                                         nullptr, nullptr, nullptr);
  // weighted mix + rank-1 expansion to G matrices
  k_mix_qk<<<4096, 128, 0, stream>>>(AHqk, fwQ, fwK, rwQ, rwK, Gq, Gk);
  k_mix_v <<<4096, 128, 0, stream>>>(AHv, fwV, rwV, Gv);
  // restore GEMMs: Q/K/V = G @ Rflat (3 jobs)
  k_gemm_bt3<1><<<768, 256, 0, stream>>>(Gq, RqkT, Qm, Gk, RqkT, Km, Gv, RvT, Vm);
  // V transpose for PV fragment loads
  k_transpose_v<<<16384, 256, 0, stream>>>(Vm, Vtr);
  // causal flash attention
  k_attn<<<1024, 256, 0, stream>>>(Qm, Km, Vtr, AOm);
  // output projection
  k_gemm_bt3<0><<<256, 256, 0, stream>>>(AOm, WOT, out,
                                         nullptr, nullptr, nullptr,
                                         nullptr, nullptr, nullptr);
}

// Round 3
// 374.343 us; speedup vs baseline: 1.2389x; 1.2389x over previous
//
#include <hip/hip_runtime.h>
#include <stdint.h>

typedef __attribute__((ext_vector_type(8))) __bf16 bf16x8;
typedef __attribute__((ext_vector_type(4))) float f32x4;
typedef __attribute__((ext_vector_type(4))) unsigned short us4;

__device__ __forceinline__ unsigned short f2b(float f){
  unsigned int u = __builtin_bit_cast(unsigned int, f);
  unsigned int r = (u + 0x7fffu + ((u >> 16) & 1u)) >> 16;
  return (unsigned short)r;
}
__device__ __forceinline__ float b2f(unsigned short h){
  unsigned int u = ((unsigned int)h) << 16;
  return __builtin_bit_cast(float, u);
}

#define KDIM 1024
#define NDIM 1024

// ---------------- prep kernels ----------------

__global__ void k_cast_bf16(const float* __restrict__ in, unsigned short* __restrict__ out, int n4){
  int i = blockIdx.x * 256 + threadIdx.x;
  if (i < n4){
    float4 v = ((const float4*)in)[i];
    us4 o; o.x = f2b(v.x); o.y = f2b(v.y); o.z = f2b(v.z); o.w = f2b(v.w);
    ((us4*)out)[i] = o;
  }
}

// out[b][c][r] = in[b][r][c], cast to bf16
__global__ void k_transpose_cast(const float* __restrict__ in, unsigned short* __restrict__ out,
                                 int rows, int cols, int total){
  int idx = blockIdx.x * 256 + threadIdx.x;
  if (idx >= total) return;
  int rc = rows * cols;
  int b = idx / rc, rem = idx - b * rc;
  int c = rem / rows, r = rem - c * rows;
  out[idx] = f2b(in[(size_t)b * rc + (size_t)r * cols + c]);
}

__global__ __launch_bounds__(128) void k_mix_qk(const unsigned short* __restrict__ allh,
    const float* __restrict__ fwq, const float* __restrict__ fwk,
    const float* __restrict__ rwq, const float* __restrict__ rwk,
    unsigned short* __restrict__ gq, unsigned short* __restrict__ gk){
  int bs = blockIdx.x; int r = threadIdx.x;
  const unsigned short* ah = allh + (size_t)bs * 1024;
  float hq = 0.f, hk = 0.f;
  float fq[8], fk[8], rq[8], rk[8];
  #pragma unroll
  for (int n = 0; n < 8; n++){ fq[n] = fwq[bs*8+n]; fk[n] = fwk[bs*8+n]; rq[n] = rwq[bs*8+n]; rk[n] = rwk[bs*8+n]; }
  #pragma unroll
  for (int n = 0; n < 8; n++){ float a = b2f(ah[n*128 + r]); hq += a * fq[n]; hk += a * fk[n]; }
  #pragma unroll
  for (int n = 0; n < 8; n++){
    gq[(size_t)bs*1024 + n*128 + r] = f2b(rq[n] * hq);
    gk[(size_t)bs*1024 + n*128 + r] = f2b(rk[n] * hk);
  }
}

__global__ __launch_bounds__(128) void k_mix_v(const unsigned short* __restrict__ allh,
    const float* __restrict__ fwv, const float* __restrict__ rwv,
    unsigned short* __restrict__ gv){
  int bs = blockIdx.x; int r = threadIdx.x;
  const unsigned short* ah = allh + (size_t)bs * 1024;
  float hv = 0.f;
  float fv[8], rv[8];
  #pragma unroll
  for (int n = 0; n < 8; n++){ fv[n] = fwv[bs*8+n]; rv[n] = rwv[bs*8+n]; }
  #pragma unroll
  for (int n = 0; n < 8; n++){ hv += b2f(ah[n*128 + r]) * fv[n]; }
  #pragma unroll
  for (int n = 0; n < 8; n++){ gv[(size_t)bs*1024 + n*128 + r] = f2b(rv[n] * hv); }
}

// Vpack [bh][s][64] -> Vtile [bh][t=s/128][dh][128]
__global__ void k_transpose_v(const unsigned short* __restrict__ Vp, unsigned short* __restrict__ Vt){
  int idx = blockIdx.x * 256 + threadIdx.x;
  int sc = idx & 127, dh = (idx >> 7) & 63, t = (idx >> 13) & 15, bh = idx >> 17;
  Vt[idx] = Vp[((size_t)(bh * 2048 + t * 128 + sc)) * 64 + dh];
}

// ---------------- GEMM: C[M,N] = A[M,K] @ Bt[N,K]^T, bf16 in, f32 acc ----------------
// OUT_MODE: 0 = f32 row-major, 1 = bf16 row-major, 2 = bf16 head-packed [bh][s][64]

__device__ __forceinline__ void load_lds16(const void* g, void* l){
  __builtin_amdgcn_global_load_lds((const __attribute__((address_space(1))) unsigned int*)g,
                                   (__attribute__((address_space(3))) unsigned int*)l, 16, 0, 0);
}

template<int OUT_MODE>
__global__ __launch_bounds__(256) void k_gemm_bt3(
    const unsigned short* __restrict__ A0, const unsigned short* __restrict__ B0, void* __restrict__ C0,
    const unsigned short* __restrict__ A1, const unsigned short* __restrict__ B1, void* __restrict__ C1,
    const unsigned short* __restrict__ A2, const unsigned short* __restrict__ B2, void* __restrict__ C2)
{
  __shared__ unsigned short Al[2][128*32];
  __shared__ unsigned short Bl[2][128*32];
  int job = blockIdx.x >> 8;
  int bid = blockIdx.x & 255;
  const unsigned short* A  = job == 0 ? A0 : (job == 1 ? A1 : A2);
  const unsigned short* Bt = job == 0 ? B0 : (job == 1 ? B1 : B2);
  void* C = job == 0 ? C0 : (job == 1 ? C1 : C2);
  int bx = bid & 7, by = bid >> 3;
  int m0 = by * 128, n0 = bx * 128;
  int tid = threadIdx.x, wid = tid >> 6, lane = tid & 63, l15 = lane & 15, g = lane >> 4;
  int wr = wid >> 1, wc = wid & 1;

  auto stage = [&](int buf, int kt){
    #pragma unroll
    for (int i = 0; i < 2; i++){
      int c = i * 256 + tid;
      load_lds16(A + (size_t)(m0 + (c >> 2)) * KDIM + kt * 32 + (c & 3) * 8,
                 &Al[buf][(i * 256 + wid * 64) * 8]);
    }
    #pragma unroll
    for (int i = 0; i < 2; i++){
      int c = i * 256 + tid;
      load_lds16(Bt + (size_t)(n0 + (c >> 2)) * KDIM + kt * 32 + (c & 3) * 8,
                 &Bl[buf][(i * 256 + wid * 64) * 8]);
    }
  };

  f32x4 acc[4][4] = {};

  stage(0, 0);
  __syncthreads();
  int cur = 0;
  const int nk = KDIM / 32;
  for (int kt = 0; kt < nk; ++kt){
    if (kt + 1 < nk) stage(cur ^ 1, kt + 1);
    bf16x8 af[4], bfv[4];
    #pragma unroll
    for (int mi = 0; mi < 4; mi++)
      af[mi] = *(const bf16x8*)&Al[cur][(wr*64 + mi*16 + l15) * 32 + g * 8];
    #pragma unroll
    for (int ni = 0; ni < 4; ni++)
      bfv[ni] = *(const bf16x8*)&Bl[cur][(wc*64 + ni*16 + l15) * 32 + g * 8];
    #pragma unroll
    for (int mi = 0; mi < 4; mi++)
      #pragma unroll
      for (int ni = 0; ni < 4; ni++)
        acc[mi][ni] = __builtin_amdgcn_mfma_f32_16x16x32_bf16(af[mi], bfv[ni], acc[mi][ni], 0, 0, 0);
    __syncthreads();
    cur ^= 1;
  }

  #pragma unroll
  for (int mi = 0; mi < 4; mi++){
    #pragma unroll
    for (int reg = 0; reg < 4; reg++){
      int row = m0 + wr*64 + mi*16 + g*4 + reg;
      #pragma unroll
      for (int ni = 0; ni < 4; ni++){
        int col = n0 + wc*64 + ni*16 + l15;
        float v = acc[mi][ni][reg];
        if (OUT_MODE == 0){
          ((float*)C)[(size_t)row * NDIM + col] = v;
        } else if (OUT_MODE == 1){
          ((unsigned short*)C)[(size_t)row * NDIM + col] = f2b(v);
        } else {
          int b = row >> 11, s = row & 2047, h = col >> 6, dh = col & 63;
          ((unsigned short*)C)[(((size_t)(b*16 + h)) * 2048 + s) * 64 + dh] = f2b(v);
        }
      }
    }
  }
}

// ---------------- causal flash attention, split-KV ----------------
// Qp,Kp: [bh][s][64] bf16 head-packed.  Vt: [bh][t128][dh][128] bf16.
// Work unit: (bh, qt, chunk). chunk covers 512 KV cols. nc(qt) = qt/8+1.
// Single-chunk q-tiles (qt<8) write AO directly; others write f32 partials.
// Partial chunk layout (floats): [64 rows][64 d] acc, then [64] m, [64] l.
#define PSTR 72
__global__ __launch_bounds__(256) void k_attn(
    const unsigned short* __restrict__ Qp_, const unsigned short* __restrict__ Kp_,
    const unsigned short* __restrict__ Vt, unsigned short* __restrict__ AO,
    float* __restrict__ Pws)
{
  __shared__ unsigned short Plds[4][16*PSTR];
  int bh = blockIdx.x / 80;
  int slot = blockIdx.x % 80;
  int qt = 0;
  for (;;){ int ncq = (qt >> 3) + 1; if (slot < ncq) break; slot -= ncq; qt++; }
  int c = slot;
  int nc = (qt >> 3) + 1;
  int b = bh >> 4, h = bh & 15;
  int q0 = qt * 64;
  int kv_lo = c * 512;
  int kv_hi = min((c + 1) * 512, (qt + 1) * 64);
  int niter = (kv_hi - kv_lo) >> 6;

  int tid = threadIdx.x, w = tid >> 6, lane = tid & 63, l15 = lane & 15, g = lane >> 4;
  const unsigned short* Qw = Qp_ + ((size_t)bh * 2048 + q0 + w*16) * 64;
  const unsigned short* Kb = Kp_ + (size_t)bh * 2048 * 64;
  const unsigned short* Vb = Vt + (size_t)bh * 16 * 64 * 128;
  unsigned short* Pw = &Plds[w][0];

  bf16x8 aq[2];
  #pragma unroll
  for (int kk = 0; kk < 2; kk++)
    aq[kk] = *(const bf16x8*)(Qw + l15*64 + kk*32 + g*8);

  const float cs = 0.125f * 1.44269504f;
  float m2[4], l_run[4];
  f32x4 acc_o[4] = {};
  #pragma unroll
  for (int r = 0; r < 4; r++){ m2[r] = -1e30f; l_run[r] = 0.f; }

  for (int it = 0; it < niter; ++it){
    int kv0 = kv_lo + it * 64;
    bool partial = (kv0 == q0);
    f32x4 s[4];
    #pragma unroll
    for (int ti = 0; ti < 4; ti++) s[ti] = (f32x4){0.f,0.f,0.f,0.f};
    #pragma unroll
    for (int ti = 0; ti < 4; ti++){
      #pragma unroll
      for (int kk = 0; kk < 2; kk++){
        bf16x8 bk = *(const bf16x8*)(Kb + ((size_t)(kv0 + ti*16 + l15)) * 64 + kk*32 + g*8);
        s[ti] = __builtin_amdgcn_mfma_f32_16x16x32_bf16(aq[kk], bk, s[ti], 0, 0, 0);
      }
    }
    #pragma unroll
    for (int reg = 0; reg < 4; reg++){
      int row = q0 + w*16 + g*4 + reg;
      float vv[4];
      #pragma unroll
      for (int ti = 0; ti < 4; ti++){
        float x = s[ti][reg] * cs;
        if (partial){
          int col = kv0 + ti*16 + l15;
          if (col > row) x = -1e30f;
        }
        vv[ti] = x;
      }
      float mt = fmaxf(fmaxf(vv[0], vv[1]), fmaxf(vv[2], vv[3]));
      #pragma unroll
      for (int off = 1; off < 16; off <<= 1) mt = fmaxf(mt, __shfl_xor(mt, off));
      float mn = fmaxf(m2[reg], mt);
      float corr = exp2f(m2[reg] - mn);
      m2[reg] = mn;
      float ps = 0.f;
      #pragma unroll
      for (int ti = 0; ti < 4; ti++){
        float p = exp2f(vv[ti] - mn);
        ps += p;
        Pw[(g*4 + reg)*PSTR + ti*16 + l15] = f2b(p);
      }
      #pragma unroll
      for (int off = 1; off < 16; off <<= 1) ps += __shfl_xor(ps, off);
      l_run[reg] = l_run[reg] * corr + ps;
      #pragma unroll
      for (int ni = 0; ni < 4; ni++) acc_o[ni][reg] *= corr;
    }
    int t128 = kv0 >> 7, koff = kv0 & 64;
    bf16x8 pa[2];
    #pragma unroll
    for (int cc = 0; cc < 2; cc++)
      pa[cc] = *(const bf16x8*)&Pw[l15*PSTR + cc*32 + g*8];
    #pragma unroll
    for (int ni = 0; ni < 4; ni++){
      #pragma unroll
      for (int cc = 0; cc < 2; cc++){
        bf16x8 bv = *(const bf16x8*)(Vb + ((size_t)(t128*64 + ni*16 + l15)) * 128 + koff + cc*32 + g*8);
        acc_o[ni] = __builtin_amdgcn_mfma_f32_16x16x32_bf16(pa[cc], bv, acc_o[ni], 0, 0, 0);
      }
    }
  }

  if (nc == 1){
    #pragma unroll
    for (int ni = 0; ni < 4; ni++){
      #pragma unroll
      for (int reg = 0; reg < 4; reg++){
        int row = q0 + w*16 + g*4 + reg;
        int dh = ni*16 + l15;
        AO[((size_t)(b*2048 + row)) * 1024 + h*64 + dh] = f2b(acc_o[ni][reg] / l_run[reg]);
      }
    }
  } else {
    int a8 = qt >> 3, r8 = qt & 7;
    int offq = qt + 4*a8*(a8-1) + r8*a8;
    float* P0 = Pws + ((size_t)(bh*80 + offq + c)) * (64*66);
    #pragma unroll
    for (int ni = 0; ni < 4; ni++){
      #pragma unroll
      for (int reg = 0; reg < 4; reg++){
        int lrow = w*16 + g*4 + reg;
        P0[lrow*64 + ni*16 + l15] = acc_o[ni][reg];
      }
    }
    if (l15 == 0){
      #pragma unroll
      for (int reg = 0; reg < 4; reg++){
        int lrow = w*16 + g*4 + reg;
        P0[64*64 + lrow] = m2[reg];
        P0[64*65 + lrow] = l_run[reg];
      }
    }
  }
}

// combine partials for qt >= 8
__global__ __launch_bounds__(256) void k_attn_reduce(const float* __restrict__ Pws,
                                                     unsigned short* __restrict__ AO){
  int blk = blockIdx.x;
  int bh = blk / 24, qt = 8 + blk % 24;
  int b = bh >> 4, h = bh & 15;
  int nc = (qt >> 3) + 1;
  int a8 = qt >> 3, r8 = qt & 7;
  int offq = qt + 4*a8*(a8-1) + r8*a8;
  const float* base = Pws + ((size_t)(bh*80 + offq)) * (64*66);
  int tid = threadIdx.x;
  int row = tid >> 2, d0 = (tid & 3) * 16;
  float M = -1e30f;
  #pragma unroll
  for (int cc = 0; cc < 4; ++cc)
    if (cc < nc) M = fmaxf(M, base[(size_t)cc*64*66 + 64*64 + row]);
  float wt[4] = {0.f, 0.f, 0.f, 0.f};
  float wsum = 0.f;
  #pragma unroll
  for (int cc = 0; cc < 4; ++cc){
    if (cc < nc){
      float wv = exp2f(base[(size_t)cc*64*66 + 64*64 + row] - M);
      wt[cc] = wv;
      wsum += wv * base[(size_t)cc*64*66 + 64*65 + row];
    }
  }
  float inv = 1.f / wsum;
  #pragma unroll
  for (int d = 0; d < 16; ++d){
    float o = 0.f;
    #pragma unroll
    for (int cc = 0; cc < 4; ++cc)
      o += (cc < nc) ? wt[cc] * base[(size_t)cc*64*66 + row*64 + d0 + d] : 0.f;
    AO[((size_t)(b*2048 + qt*64 + row)) * 1024 + h*64 + d0 + d] = f2b(o * inv);
  }
}

// ---------------- launch ----------------

extern "C" void kernel_launch(void* const* d_in, const int* in_sizes, int n_in,
                              void* d_out, int out_size, void* d_ws, size_t ws_size,
                              hipStream_t stream){
  const float* x    = (const float*)d_in[0];
  const float* fqk  = (const float*)d_in[1];
  const float* fv   = (const float*)d_in[2];
  const float* rqk  = (const float*)d_in[3];
  const float* rv   = (const float*)d_in[4];
  const float* fwQ  = (const float*)d_in[5];
  const float* fwK  = (const float*)d_in[6];
  const float* fwV  = (const float*)d_in[7];
  const float* rwQ  = (const float*)d_in[8];
  const float* rwK  = (const float*)d_in[9];
  const float* rwV  = (const float*)d_in[10];
  const float* wo   = (const float*)d_in[11];
  float* out = (float*)d_out;

  char* ws = (char*)d_ws;
  size_t off = 0;
  auto alloc = [&](size_t bytes)->void*{
    void* p = ws + off; off += (bytes + 255) & ~(size_t)255; return p;
  };
  // weights first (WOT must survive to the end)
  unsigned short* FqkT = (unsigned short*)alloc(1024ull*1024*2);
  unsigned short* FvT  = (unsigned short*)alloc(1024ull*1024*2);
  unsigned short* RqkT = (unsigned short*)alloc(1024ull*1024*2);
  unsigned short* RvT  = (unsigned short*)alloc(1024ull*1024*2);
  unsigned short* WOT  = (unsigned short*)alloc(1024ull*1024*2);
  // overlay region: dead before attention runs; reused as split-KV partials
  char* overlay = ws + off;
  unsigned short* Xbf  = (unsigned short*)alloc(4096ull*1024*2);
  unsigned short* AHqk = (unsigned short*)alloc(4096ull*1024*2);
  unsigned short* AHv  = (unsigned short*)alloc(4096ull*1024*2);
  unsigned short* Gq   = (unsigned short*)alloc(4096ull*1024*2);
  unsigned short* Gk   = (unsigned short*)alloc(4096ull*1024*2);
  unsigned short* Gv   = (unsigned short*)alloc(4096ull*1024*2);
  // live through attention
  unsigned short* Qp   = (unsigned short*)alloc(4096ull*1024*2);
  unsigned short* Kp   = (unsigned short*)alloc(4096ull*1024*2);
  unsigned short* Vpk  = (unsigned short*)alloc(4096ull*1024*2);
  unsigned short* Vtl  = (unsigned short*)alloc(32ull*16*64*128*2);
  unsigned short* AOm  = (unsigned short*)alloc(4096ull*1024*2);
  float* Pws = (float*)overlay;  // 2560 * 64*66 * 4B = 43.3MB < 48MB overlay

  // pack/cast
  k_cast_bf16<<<4096, 256, 0, stream>>>(x, Xbf, 4096*1024/4);
  k_transpose_cast<<<4096, 256, 0, stream>>>(fqk, FqkT, 1024, 128, 8*1024*128);
  k_transpose_cast<<<4096, 256, 0, stream>>>(fv,  FvT,  1024, 128, 8*1024*128);
  k_transpose_cast<<<4096, 256, 0, stream>>>(rqk, RqkT, 1024, 1024, 1024*1024);
  k_transpose_cast<<<4096, 256, 0, stream>>>(rv,  RvT,  1024, 1024, 1024*1024);
  k_transpose_cast<<<4096, 256, 0, stream>>>(wo,  WOT,  1024, 1024, 1024*1024);

  // feature GEMMs: all_h = X @ F^T  (2 jobs, bf16 row-major out)
  k_gemm_bt3<1><<<512, 256, 0, stream>>>(Xbf, FqkT, AHqk, Xbf, FvT, AHv,
                                         nullptr, nullptr, nullptr);
  // weighted mix + rank-1 expansion to G matrices
  k_mix_qk<<<4096, 128, 0, stream>>>(AHqk, fwQ, fwK, rwQ, rwK, Gq, Gk);
  k_mix_v <<<4096, 128, 0, stream>>>(AHv, fwV, rwV, Gv);
  // restore GEMMs -> head-packed Q/K/V
  k_gemm_bt3<2><<<768, 256, 0, stream>>>(Gq, RqkT, Qp, Gk, RqkT, Kp, Gv, RvT, Vpk);
  // V tiling for PV fragment loads
  k_transpose_v<<<16384, 256, 0, stream>>>(Vpk, Vtl);
  // causal flash attention, split-KV balanced
  k_attn<<<2560, 256, 0, stream>>>(Qp, Kp, Vtl, AOm, Pws);
  k_attn_reduce<<<768, 256, 0, stream>>>(Pws, AOm);
  // output projection
  k_gemm_bt3<0><<<256, 256, 0, stream>>>(AOm, WOT, out,
                                         nullptr, nullptr, nullptr,
                                         nullptr, nullptr, nullptr);
}